// Round 1
// 230.204 us; speedup vs baseline: 1.0011x; 1.0011x over previous
//
#include <hip/hip_runtime.h>

typedef __attribute__((ext_vector_type(8))) short bf16x8;
typedef __attribute__((ext_vector_type(4))) float f32x4;

#define L2E 1.44269504088896340736f

// RNE fp32->bf16 pair pack in ONE VALU op (gfx950 v_cvt_pk_bf16_f32).
// Replaces the ~10-op bit-twiddle sequence; rounding is identical (RNE).
__device__ __forceinline__ unsigned pk2(float lo, float hi) {
    unsigned r;
    asm("v_cvt_pk_bf16_f32 %0, %1, %2" : "=v"(r) : "v"(lo), "v"(hi));
    return r;
}

constexpr int D_   = 64;
constexpr int SEQ  = 4096;
constexpr int MQ   = 128;   // queries per block
constexpr int CK   = 128;   // keys per chunk
constexpr int KSTR = 72;    // k_lds row stride (ushorts): 144B -> bank 4r, b128-aligned
constexpr int VSTR = 132;   // v_lds row stride (ushorts): 264B -> conflict-free b64
constexpr int OSTR = 68;    // o_lds row stride (floats):  272B, 16B-aligned

// smem: K tile 128*72*2 = 18432 B, Vt tile 64*132*2 = 16896 B (sum 35328)
// epilogue overlays O tile 128*68*4 = 34816 B
constexpr int SMEM_BYTES = 35840;

__global__ __launch_bounds__(256, 2)
void swattn_kernel(const float* __restrict__ Qg, const float* __restrict__ Kg,
                   const float* __restrict__ Vg, float* __restrict__ Og)
{
    __shared__ __align__(16) char smem[SMEM_BYTES];
    unsigned short* k_lds = (unsigned short*)smem;
    unsigned short* v_lds = (unsigned short*)(smem + CK * KSTR * 2);
    float*          o_lds = (float*)smem;

    const int tid  = threadIdx.x;
    const int wv   = tid >> 6;        // wave 0..3: owns queries [32w, 32w+32)
    const int lane = tid & 63;
    const int g    = lane >> 4;       // lane quad 0..3
    const int n    = lane & 15;

    const int bh = blockIdx.x & 63;   // head-fastest => 3-qb K/V reuse is temporally close
    const int qb = blockIdx.x >> 6;   // 0..31
    const size_t base = (size_t)bh * SEQ * D_;
    const int q0 = qb * MQ;

    // ---- Q fragments (B operand of S^T = K*Q^T): B[k=d][n=query], held in regs ----
    // lane needs Q[q0+32w+16nt+n][d = 32ks + 8g .. +7], pre-scaled by 1/sqrt(64)
    bf16x8 qf[2][2];
    #pragma unroll
    for (int nt = 0; nt < 2; ++nt) {
        const float* qp = Qg + base + (size_t)(q0 + wv * 32 + nt * 16 + n) * D_;
        #pragma unroll
        for (int ks = 0; ks < 2; ++ks) {
            f32x4 a = *(const f32x4*)(qp + ks * 32 + g * 8);
            f32x4 b = *(const f32x4*)(qp + ks * 32 + g * 8 + 4);
            union { bf16x8 v; unsigned u[4]; } t;
            t.u[0] = pk2(a.x * 0.125f, a.y * 0.125f);
            t.u[1] = pk2(a.z * 0.125f, a.w * 0.125f);
            t.u[2] = pk2(b.x * 0.125f, b.y * 0.125f);
            t.u[3] = pk2(b.z * 0.125f, b.w * 0.125f);
            qf[nt][ks] = t.v;
        }
    }

    // O^T accumulators: tiles [mtd=d/16][nt=query/16], C layout row=d%16, col=query%16
    f32x4 o_ac[4][2];
    #pragma unroll
    for (int a = 0; a < 4; ++a)
        #pragma unroll
        for (int b = 0; b < 2; ++b)
            o_ac[a][b] = f32x4{0.f, 0.f, 0.f, 0.f};
    float m_r[2] = {-1e30f, -1e30f};
    float l_r[2] = {0.0f, 0.0f};

    #pragma unroll
    for (int ci = 0; ci < 3; ++ci) {
        const int cb = qb - 2 + ci;       // key chunk index (uniform across block)
        if (cb < 0) continue;             // keys j<0 don't exist

        __syncthreads();                  // prior chunk's LDS reads done

        // ---- stage K chunk -> k_lds[key][d] bf16 ----
        {
            const f32x4* kp = (const f32x4*)(Kg + base + (size_t)cb * CK * D_);
            #pragma unroll
            for (int i = 0; i < 8; ++i) {
                int idx = tid + 256 * i;          // float4 index; 16 per key row
                int row = idx >> 4, c4 = idx & 15;
                f32x4 x = kp[idx];
                *(uint2*)&k_lds[row * KSTR + c4 * 4] =
                    make_uint2(pk2(x.x, x.y), pk2(x.z, x.w));
            }
        }
        // ---- stage V chunk transposed -> v_lds[d][key] bf16 ----
        {
            const f32x4* vp = (const f32x4*)(Vg + base + (size_t)cb * CK * D_);
            const int g16 = tid & 15, kq = tid >> 4;
            #pragma unroll
            for (int h = 0; h < 2; ++h) {
                int key0 = (kq + 16 * h) * 4;
                union { f32x4 v; float f[4]; } r0, r1, r2, r3;
                r0.v = vp[(key0 + 0) * 16 + g16];
                r1.v = vp[(key0 + 1) * 16 + g16];
                r2.v = vp[(key0 + 2) * 16 + g16];
                r3.v = vp[(key0 + 3) * 16 + g16];
                #pragma unroll
                for (int i = 0; i < 4; ++i) {
                    *(uint2*)&v_lds[(g16 * 4 + i) * VSTR + key0] =
                        make_uint2(pk2(r0.f[i], r1.f[i]), pk2(r2.f[i], r3.f[i]));
                }
            }
        }
        __syncthreads();

        // ---- S^T = K * Q^T : m=key (8 tiles), n=query (2 tiles), k=d (2 steps) ----
        f32x4 sc[8][2];
        #pragma unroll
        for (int mt = 0; mt < 8; ++mt)
            #pragma unroll
            for (int nt = 0; nt < 2; ++nt)
                sc[mt][nt] = f32x4{0.f, 0.f, 0.f, 0.f};

        __builtin_amdgcn_s_setprio(1);
        #pragma unroll
        for (int ks = 0; ks < 2; ++ks) {
            #pragma unroll
            for (int mt = 0; mt < 8; ++mt) {
                // A frag of K: lane reads K[key=16mt+n][d=32ks+8g..+7], 16B, conflict-free
                bf16x8 af = *(const bf16x8*)&k_lds[(mt * 16 + n) * KSTR + ks * 32 + g * 8];
                sc[mt][0] = __builtin_amdgcn_mfma_f32_16x16x32_bf16(af, qf[0][ks], sc[mt][0], 0, 0, 0);
                sc[mt][1] = __builtin_amdgcn_mfma_f32_16x16x32_bf16(af, qf[1][ks], sc[mt][1], 0, 0, 0);
            }
        }
        __builtin_amdgcn_s_setprio(0);

        // ---- band mask: lane holds key kk=16mt+4g+r (row), query q=32wv+16nt+n (col) ----
        // global i = qb*128+q, j = cb*128+kk; ci=0: j>=i-256 <=> kk>=q; ci=2: j<=i <=> kk<=q
        if (ci != 1) {
            #pragma unroll
            for (int mt = 0; mt < 8; ++mt)
                #pragma unroll
                for (int nt = 0; nt < 2; ++nt)
                    #pragma unroll
                    for (int r = 0; r < 4; ++r) {
                        int kk = mt * 16 + g * 4 + r;
                        int qq = wv * 32 + nt * 16 + n;   // FULL block-local query index
                        bool ok = (ci == 0) ? (kk >= qq) : (kk <= qq);
                        if (!ok) sc[mt][nt][r] = -1e30f;
                    }
        }

        // ---- online softmax (per query col), base-2; tree-shaped reductions ----
        uint2 pkv[8][2];  // P^T packed bf16 pairs, still in C layout
        #pragma unroll
        for (int nt = 0; nt < 2; ++nt) {
            float t8[8];
            #pragma unroll
            for (int mt = 0; mt < 8; ++mt)
                t8[mt] = fmaxf(fmaxf(sc[mt][nt][0], sc[mt][nt][1]),
                               fmaxf(sc[mt][nt][2], sc[mt][nt][3]));
            float ma = fmaxf(t8[0], t8[1]), mb = fmaxf(t8[2], t8[3]);
            float mc = fmaxf(t8[4], t8[5]), md = fmaxf(t8[6], t8[7]);
            float mx = fmaxf(fmaxf(ma, mb), fmaxf(mc, md));
            mx = fmaxf(mx, __shfl_xor(mx, 16, 64));
            mx = fmaxf(mx, __shfl_xor(mx, 32, 64));
            float mnew = fmaxf(m_r[nt], mx);
            float al   = __builtin_amdgcn_exp2f((m_r[nt] - mnew) * L2E);
            m_r[nt] = mnew;
            float c  = -mnew * L2E;
            float s8[8];
            #pragma unroll
            for (int mt = 0; mt < 8; ++mt) {
                float p0 = __builtin_amdgcn_exp2f(fmaf(sc[mt][nt][0], L2E, c));
                float p1 = __builtin_amdgcn_exp2f(fmaf(sc[mt][nt][1], L2E, c));
                float p2 = __builtin_amdgcn_exp2f(fmaf(sc[mt][nt][2], L2E, c));
                float p3 = __builtin_amdgcn_exp2f(fmaf(sc[mt][nt][3], L2E, c));
                s8[mt] = (p0 + p1) + (p2 + p3);
                pkv[mt][nt] = make_uint2(pk2(p0, p1), pk2(p2, p3));
            }
            float ra = s8[0] + s8[1], rb = s8[2] + s8[3];
            float rc = s8[4] + s8[5], rd = s8[6] + s8[7];
            float rs = (ra + rb) + (rc + rd);
            rs += __shfl_xor(rs, 16, 64);
            rs += __shfl_xor(rs, 32, 64);
            l_r[nt] = l_r[nt] * al + rs;
            #pragma unroll
            for (int mtd = 0; mtd < 4; ++mtd)
                #pragma unroll
                for (int r = 0; r < 4; ++r)
                    o_ac[mtd][nt][r] *= al;
        }

        // ---- O^T += V^T * P^T. Contraction-order trick: key slot kappa(g,j) =
        // 32*kp4 + 16*(j>>2) + 4g + (j&3), so B frag = lane's own pkv dwords and
        // A frag = two contiguous ds_read_b64 from v_lds. No cross-lane moves. ----
        __builtin_amdgcn_s_setprio(1);
        #pragma unroll
        for (int kp4 = 0; kp4 < 4; ++kp4) {
            bf16x8 bfr[2];
            #pragma unroll
            for (int nt = 0; nt < 2; ++nt) {
                union { bf16x8 v; uint2 u2[2]; } bb;
                bb.u2[0] = pkv[2 * kp4][nt];
                bb.u2[1] = pkv[2 * kp4 + 1][nt];
                bfr[nt] = bb.v;
            }
            #pragma unroll
            for (int mtd = 0; mtd < 4; ++mtd) {
                int bus = (mtd * 16 + n) * VSTR + kp4 * 32 + g * 4;
                union { bf16x8 v; uint2 u2[2]; } aa;
                aa.u2[0] = *(const uint2*)&v_lds[bus];
                aa.u2[1] = *(const uint2*)&v_lds[bus + 16];
                o_ac[mtd][0] = __builtin_amdgcn_mfma_f32_16x16x32_bf16(aa.v, bfr[0], o_ac[mtd][0], 0, 0, 0);
                o_ac[mtd][1] = __builtin_amdgcn_mfma_f32_16x16x32_bf16(aa.v, bfr[1], o_ac[mtd][1], 0, 0, 0);
            }
        }
        __builtin_amdgcn_s_setprio(0);
    }

    // ---- epilogue: 1/l scale, transpose via LDS, coalesced fp32 stores ----
    __syncthreads();   // everyone done with k_lds/v_lds before overlaying o_lds
    float inv[2] = {1.0f / l_r[0], 1.0f / l_r[1]};
    #pragma unroll
    for (int mtd = 0; mtd < 4; ++mtd)
        #pragma unroll
        for (int nt = 0; nt < 2; ++nt) {
            f32x4 v = o_ac[mtd][nt];
            v.x *= inv[nt]; v.y *= inv[nt]; v.z *= inv[nt]; v.w *= inv[nt];
            // lane holds O[q = 32w+16nt+n][d = 16mtd+4g .. +3] -> 16B LDS store
            *(f32x4*)&o_lds[(wv * 32 + nt * 16 + n) * OSTR + mtd * 16 + g * 4] = v;
        }
    __syncthreads();

    f32x4* op = (f32x4*)(Og + base + (size_t)q0 * D_);
    #pragma unroll
    for (int p = 0; p < 8; ++p) {
        int row = p * 16 + (tid >> 4);
        int c4  = tid & 15;
        f32x4 v = *(const f32x4*)&o_lds[row * OSTR + c4 * 4];
        op[row * 16 + c4] = v;                 // 16 lanes x 16B contiguous per row
    }
}

extern "C" void kernel_launch(void* const* d_in, const int* in_sizes, int n_in,
                              void* d_out, int out_size, void* d_ws, size_t ws_size,
                              hipStream_t stream) {
    (void)in_sizes; (void)n_in; (void)out_size; (void)d_ws; (void)ws_size;
    const float* q = (const float*)d_in[0];
    const float* k = (const float*)d_in[1];
    const float* v = (const float*)d_in[2];
    float* o = (float*)d_out;
    dim3 grid(64 * 32), block(256);   // blockIdx = qb*64 + bh
    hipLaunchKernelGGL(swattn_kernel, grid, block, 0, stream, q, k, v, o);
}